// Round 12
// baseline (347.665 us; speedup 1.0000x reference)
//
#include <hip/hip_runtime.h>

#define N_ATOMS 10000
#define N_EDGES 160000
#define N_STRUCT 8
#define D_PAD 48             // max slots per atom; P(Poisson(16) > 48) ~ 2e-7 overall
#define EDW 48               // floats per slot: [0..15]=sh, [16..31]=R, [32..47]=hs
#define N_SLOTS (N_ATOMS * D_PAD)
#define B4 4                 // slots per register batch
#define PI_F 3.14159265358979323846f

// ---------------- setup ----------------

__global__ void init_kernel(int* __restrict__ cursor, float* __restrict__ accum) {
    int i = blockIdx.x * blockDim.x + threadIdx.x;
    if (i < N_ATOMS) cursor[i] = i * D_PAD;
    if (i < N_STRUCT) accum[i] = 0.f;
}

__global__ void scatter_kernel(const int* __restrict__ receivers, int* __restrict__ cursor,
                               int* __restrict__ perm) {
    int e = blockIdx.x * blockDim.x + threadIdx.x;
    if (e < N_EDGES) perm[e] = atomicAdd(&cursor[receivers[e]], 1);
}

// zero ONLY the pad slots [cnt, ceil4(cnt)) of each atom (all 48 floats)
__global__ void pad_kernel(const int* __restrict__ cursor, float* __restrict__ edat) {
    int i = blockIdx.x * blockDim.x + threadIdx.x;
    if (i >= N_ATOMS * 3) return;
    int a = i / 3, j = i % 3;
    int cnt = cursor[a] - a * D_PAD;
    if (cnt > D_PAD) cnt = D_PAD;
    int c4 = (cnt + B4 - 1) / B4 * B4;
    if (c4 > D_PAD) c4 = D_PAD;
    int slot = cnt + j;
    if (slot < c4) {
        float4 z = make_float4(0.f, 0.f, 0.f, 0.f);
        float4* p = (float4*)(edat + (size_t)(a * D_PAD + slot) * EDW);
        #pragma unroll
        for (int k = 0; k < 12; ++k) p[k] = z;
    }
}

__global__ void emb_kernel(const float* __restrict__ embed, const int* __restrict__ species,
                           float* __restrict__ h0) {
    int i = blockIdx.x * blockDim.x + threadIdx.x;
    if (i < N_ATOMS * 16) {
        int a = i >> 4, c = i & 15;
        h0[i] = embed[species[a] * 16 + c];
    }
}

// count-aware hs materialization: real slots only (~160K x 64 B = 10 MB)
__global__ void gather_hs(const int* __restrict__ snd, const int* __restrict__ cursor,
                          const float* __restrict__ h, float* __restrict__ edat) {
    int slot = blockIdx.x * blockDim.x + threadIdx.x;
    if (slot >= N_SLOTS) return;
    int a = slot / D_PAD, j = slot - a * D_PAD;
    int cnt = cursor[a] - a * D_PAD;
    if (cnt > D_PAD) cnt = D_PAD;
    if (j >= cnt) return;                     // pad hs already zeroed by pad_kernel
    int s = snd[slot];
    const float4* hp = (const float4*)(h + (size_t)s * 16);
    float4* ep = (float4*)(edat + (size_t)slot * EDW + 32);
    ep[0] = hp[0]; ep[1] = hp[1]; ep[2] = hp[2]; ep[3] = hp[3];
}

// transpose W_inv [256,16] -> W_invT [16,256] (both layers, one tiny launch)
__global__ void transpose_winv(const float* __restrict__ A, const float* __restrict__ B,
                               float* __restrict__ AT, float* __restrict__ BT) {
    int i = blockIdx.x * blockDim.x + threadIdx.x;
    if (i < 4096) {
        int k = i >> 4, c = i & 15;
        AT[c * 256 + k] = A[i];
    } else if (i < 8192) {
        int j = i - 4096;
        int k = j >> 4, c = j & 15;
        BT[c * 256 + k] = B[j];
    }
}

// ---------------- edge geometry -> slots ----------------

__global__ void edge_geom(const float* __restrict__ pos, const float* __restrict__ W_rad,
                          const int* __restrict__ senders, const int* __restrict__ receivers,
                          const int* __restrict__ perm,
                          float* __restrict__ edat, int* __restrict__ snd) {
    int e = blockIdx.x * blockDim.x + threadIdx.x;
    if (e >= N_EDGES) return;
    int s = senders[e], rc = receivers[e];
    int p = perm[e];
    float dx = pos[rc * 3 + 0] - pos[s * 3 + 0];
    float dy = pos[rc * 3 + 1] - pos[s * 3 + 1];
    float dz = pos[rc * 3 + 2] - pos[s * 3 + 2];
    float r = sqrtf(dx * dx + dy * dy + dz * dz);
    float rr = fmaxf(r, 1e-6f);
    float inv = 1.0f / rr;
    float x = dx * inv, y = dy * inv, z = dz * inv;
    float x2 = x * x, y2 = y * y, z2 = z * z;
    float she[16];
    she[0]  = 0.28209479f;
    she[1]  = 0.48860251f * y;
    she[2]  = 0.48860251f * z;
    she[3]  = 0.48860251f * x;
    she[4]  = 1.09254843f * x * y;
    she[5]  = 1.09254843f * y * z;
    she[6]  = 0.31539157f * (3.0f * z2 - 1.0f);
    she[7]  = 1.09254843f * x * z;
    she[8]  = 0.54627422f * (x2 - y2);
    she[9]  = 0.59004359f * y * (3.0f * x2 - y2);
    she[10] = 2.89061144f * x * y * z;
    she[11] = 0.45704579f * y * (5.0f * z2 - 1.0f);
    she[12] = 0.37317633f * z * (5.0f * z2 - 3.0f);
    she[13] = 0.45704579f * x * (5.0f * z2 - 1.0f);
    she[14] = 1.44530572f * z * (x2 - y2);
    she[15] = 0.59004359f * x * (x2 - 3.0f * y2);
    float* ed = edat + (size_t)p * EDW;
    ((float4*)ed)[0] = make_float4(she[0], she[1], she[2], she[3]);
    ((float4*)ed)[1] = make_float4(she[4], she[5], she[6], she[7]);
    ((float4*)ed)[2] = make_float4(she[8], she[9], she[10], she[11]);
    ((float4*)ed)[3] = make_float4(she[12], she[13], she[14], she[15]);
    float fc = 0.5f * (cosf(PI_F * fminf(r * 0.2f, 1.0f)) + 1.0f);
    const float c0 = 0.6324555320336759f; // sqrt(2/5)
    float bfv[8];
    #pragma unroll
    for (int n = 0; n < 8; ++n)
        bfv[n] = c0 * sinf((float)(n + 1) * PI_F * rr * 0.2f) * inv * fc;
    float Re[16];
    #pragma unroll
    for (int l = 0; l < 4; ++l) {
        #pragma unroll
        for (int n = 0; n < 4; ++n) {
            float acc = 0.0f;
            #pragma unroll
            for (int b = 0; b < 8; ++b) acc = fmaf(bfv[b], W_rad[l * 32 + b * 4 + n], acc);
            Re[l * 4 + n] = acc;
        }
    }
    ((float4*)ed)[4] = make_float4(Re[0], Re[1], Re[2], Re[3]);
    ((float4*)ed)[5] = make_float4(Re[4], Re[5], Re[6], Re[7]);
    ((float4*)ed)[6] = make_float4(Re[8], Re[9], Re[10], Re[11]);
    ((float4*)ed)[7] = make_float4(Re[12], Re[13], Re[14], Re[15]);
    snd[p] = s;
}

// ---------------- fused MP layer (R11's passing kernel, unchanged) ----------------

__global__ __launch_bounds__(64, 7) void mp_layer(
    const float* __restrict__ edat,
    const int* __restrict__ cursor,
    const float* __restrict__ W_invT,
    const float* __restrict__ cemb, float* __restrict__ h_out,
    const float* __restrict__ w_out, const float* __restrict__ comp_w,
    const int* __restrict__ species, const int* __restrict__ sids,
    float* __restrict__ accum, int do_energy)
{
    __shared__ __attribute__((aligned(16))) float wl[1088]; // one wave's scratch
    const int lane = threadIdx.x;                  // block = 1 wave
    const int atom = blockIdx.x;                   // 10000 blocks
    const int m = lane >> 2, cg = lane & 3;
    const int l = (m >= 9) ? 3 : (m >= 4) ? 2 : (m >= 1) ? 1 : 0;
    const int l4 = l * 4, cg4 = cg * 4;

    int cnt = cursor[atom] - atom * D_PAD;
    if (cnt > D_PAD) cnt = D_PAD;
    const int nb = (cnt + B4 - 1) / B4;            // real 4-slot batches (pads zeroed)

    const float* strip = edat + (size_t)atom * (D_PAD * EDW);

    float acc[4][4];  // [n][j] ; A[m][n][c=cg*4+j]
    #pragma unroll
    for (int n = 0; n < 4; ++n)
        #pragma unroll
        for (int j = 0; j < 4; ++j) acc[n][j] = 0.f;

    for (int b = 0; b < nb; ++b) {
        const float* bp = strip + b * (B4 * EDW);
        float  shv[B4];
        float4 rv[B4];
        float4 hv[B4];
        #pragma unroll
        for (int q = 0; q < B4; ++q) {
            const float* eq = bp + q * EDW;
            shv[q] = eq[m];
            rv[q]  = *(const float4*)(eq + 16 + l4);
            hv[q]  = *(const float4*)(eq + 32 + cg4);
        }
        #pragma unroll
        for (int q = 0; q < B4; ++q) {
            float hvj[4] = {hv[q].x, hv[q].y, hv[q].z, hv[q].w};
            float rvn[4] = {rv[q].x, rv[q].y, rv[q].z, rv[q].w};
            #pragma unroll
            for (int j = 0; j < 4; ++j) {
                float ww = shv[q] * hvj[j];
                #pragma unroll
                for (int n = 0; n < 4; ++n)
                    acc[n][j] = fmaf(ww, rvn[n], acc[n][j]);
            }
        }
    }

    // ---- per-wave epilogue ----
    const float sc_l[4] = {1.0f, 0.57735026918962576f, 0.44721359549995794f, 0.37796447300922720f};
    #pragma unroll
    for (int n = 0; n < 4; ++n)
        *(float4*)&wl[m * 68 + n * 16 + cg4] =
            make_float4(acc[n][0], acc[n][1], acc[n][2], acc[n][3]);

    float inv4[4];
    #pragma unroll
    for (int i = 0; i < 4; ++i) {
        const int kt = lane * 4 + i;
        const int le = kt >> 6, k64 = kt & 63;
        const int m0 = le * le, m1 = m0 + 2 * le;
        float s = 0.f;
        for (int mm = m0; mm <= m1; ++mm) {
            float v = wl[mm * 68 + k64];
            s = fmaf(v, v, s);
        }
        inv4[i] = s * sc_l[le];
    }

    if (do_energy) {
        float s = 0.f;
        #pragma unroll
        for (int i = 0; i < 4; ++i) s = fmaf(inv4[i], w_out[lane * 4 + i], s);
        #pragma unroll
        for (int off = 32; off > 0; off >>= 1) s += __shfl_down(s, off);
        if (lane == 0) atomicAdd(&accum[sids[atom]], s + comp_w[species[atom]]);
    } else {
        *(float4*)&wl[lane * 4] = make_float4(inv4[0], inv4[1], inv4[2], inv4[3]);
        const int c = lane & 15, q4 = lane >> 4;
        const float* wrow = W_invT + c * 256 + q4 * 64;
        float p = 0.f;
        #pragma unroll
        for (int kk = 0; kk < 16; ++kk) {
            float4 iv = *(const float4*)&wl[q4 * 64 + kk * 4];
            float4 wv = *(const float4*)(wrow + kk * 4);
            p = fmaf(iv.x, wv.x, p);
            p = fmaf(iv.y, wv.y, p);
            p = fmaf(iv.z, wv.z, p);
            p = fmaf(iv.w, wv.w, p);
        }
        p += __shfl_xor(p, 16);
        p += __shfl_xor(p, 32);
        if (lane < 16) h_out[atom * 16 + c] = p * cemb[atom * 16 + c];
    }
}

__global__ void out_kernel(const float* __restrict__ accum, float* __restrict__ out) {
    int t = threadIdx.x;
    if (t < N_STRUCT) out[t] = accum[t];
}

// ================ DIAGNOSTIC PROBES (run after the real pipeline; ================
// ================ write only to a scratch dummy buffer)            ================

// clock meter: pure-VALU, 8 independent FMA chains x 400 iters, 8 waves/SIMD.
// @2.4 GHz predicted ~21 us; if >~80 us the core clock is collapsed during
// latency-shaped dispatches and ALL prior analysis scales by that factor.
__global__ __launch_bounds__(256) void probe_valu(float* __restrict__ dummy) {
    float a0 = (float)((blockIdx.x & 7) + 1) * 0.1f;
    float a1 = a0 + 0.01f, a2 = a0 + 0.02f, a3 = a0 + 0.03f;
    float a4 = a0 + 0.04f, a5 = a0 + 0.05f, a6 = a0 + 0.06f, a7 = a0 + 0.07f;
    #pragma unroll 1
    for (int i = 0; i < 400; ++i) {
        a0 = fmaf(a0, 0.9999999f, 1e-9f);
        a1 = fmaf(a1, 0.9999998f, 1e-9f);
        a2 = fmaf(a2, 0.9999997f, 1e-9f);
        a3 = fmaf(a3, 0.9999996f, 1e-9f);
        a4 = fmaf(a4, 0.9999995f, 1e-9f);
        a5 = fmaf(a5, 0.9999994f, 1e-9f);
        a6 = fmaf(a6, 0.9999993f, 1e-9f);
        a7 = fmaf(a7, 0.9999992f, 1e-9f);
    }
    dummy[blockIdx.x * 256 + threadIdx.x] =
        a0 + a1 + a2 + a3 + a4 + a5 + a6 + a7;
}

// max-efficiency pattern: whole strip as lane-contiguous dwordx4 (1024 B/instr).
// Reads the same 92 MB. Predicted 15-30 us if BW is available to this kernel shape.
__global__ __launch_bounds__(64, 7) void probe_wide(const float* __restrict__ edat,
                                                    float* __restrict__ dummy) {
    const int lane = threadIdx.x;
    const int atom = blockIdx.x;
    const float4* strip = (const float4*)(edat + (size_t)atom * (D_PAD * EDW));
    float s = 0.f;
    #pragma unroll
    for (int j = 0; j < 9; ++j) {
        float4 v = strip[j * 64 + lane];
        s += v.x + v.y + v.z + v.w;
    }
    dummy[atom * 64 + lane] = s;
}

// mp_layer's EXACT hot loop (same pattern, control flow, LDS footprint, launch
// shape) with the epilogue deleted. If this ~=130 us the load phase is guilty;
// if ~15-25 us the epilogue carries the hidden cost.
__global__ __launch_bounds__(64, 7) void probe_loads(const float* __restrict__ edat,
                                                     const int* __restrict__ cursor,
                                                     float* __restrict__ dummy) {
    __shared__ __attribute__((aligned(16))) float wl[1088];
    const int lane = threadIdx.x;
    const int atom = blockIdx.x;
    const int m = lane >> 2, cg = lane & 3;
    const int l = (m >= 9) ? 3 : (m >= 4) ? 2 : (m >= 1) ? 1 : 0;
    const int l4 = l * 4, cg4 = cg * 4;

    int cnt = cursor[atom] - atom * D_PAD;
    if (cnt > D_PAD) cnt = D_PAD;
    const int nb = (cnt + B4 - 1) / B4;

    const float* strip = edat + (size_t)atom * (D_PAD * EDW);

    float acc[4][4];
    #pragma unroll
    for (int n = 0; n < 4; ++n)
        #pragma unroll
        for (int j = 0; j < 4; ++j) acc[n][j] = 0.f;

    for (int b = 0; b < nb; ++b) {
        const float* bp = strip + b * (B4 * EDW);
        float  shv[B4];
        float4 rv[B4];
        float4 hv[B4];
        #pragma unroll
        for (int q = 0; q < B4; ++q) {
            const float* eq = bp + q * EDW;
            shv[q] = eq[m];
            rv[q]  = *(const float4*)(eq + 16 + l4);
            hv[q]  = *(const float4*)(eq + 32 + cg4);
        }
        #pragma unroll
        for (int q = 0; q < B4; ++q) {
            float hvj[4] = {hv[q].x, hv[q].y, hv[q].z, hv[q].w};
            float rvn[4] = {rv[q].x, rv[q].y, rv[q].z, rv[q].w};
            #pragma unroll
            for (int j = 0; j < 4; ++j) {
                float ww = shv[q] * hvj[j];
                #pragma unroll
                for (int n = 0; n < 4; ++n)
                    acc[n][j] = fmaf(ww, rvn[n], acc[n][j]);
            }
        }
    }

    float s = 0.f;
    #pragma unroll
    for (int n = 0; n < 4; ++n)
        #pragma unroll
        for (int j = 0; j < 4; ++j) s += acc[n][j];
    wl[lane] = s;                              // keep LDS footprint identical
    dummy[atom * 64 + lane] = s + wl[lane ^ 1];
}

// ---------------- launch ----------------

extern "C" void kernel_launch(void* const* d_in, const int* in_sizes, int n_in,
                              void* d_out, int out_size, void* d_ws, size_t ws_size,
                              hipStream_t stream) {
    const float* positions = (const float*)d_in[0];
    const float* embed     = (const float*)d_in[1];
    const float* W_rad     = (const float*)d_in[2];
    const float* W_inv1    = (const float*)d_in[3];
    const float* W_inv2    = (const float*)d_in[4];
    const float* w_out     = (const float*)d_in[5];
    const float* comp_w    = (const float*)d_in[6];
    const int* senders    = (const int*)d_in[7];
    const int* receivers  = (const int*)d_in[8];
    const int* species    = (const int*)d_in[9];
    const int* sids       = (const int*)d_in[10];
    float* out = (float*)d_out;

    char* ws = (char*)d_ws;
    size_t off = 0;
    auto alloc = [&](size_t bytes) -> void* {
        void* p = ws + off;
        off = (off + bytes + 255) & ~(size_t)255;
        return p;
    };
    float* edat     = (float*)alloc((size_t)N_SLOTS * EDW * 4);   // 92.2 MB
    float* h0       = (float*)alloc((size_t)N_ATOMS * 16 * 4);
    float* h1       = (float*)alloc((size_t)N_ATOMS * 16 * 4);
    int*   cursor   = (int*)alloc((size_t)N_ATOMS * 4);
    int*   perm     = (int*)alloc((size_t)N_EDGES * 4);
    int*   snd      = (int*)alloc((size_t)N_SLOTS * 4);
    float* accum    = (float*)alloc(8 * 4);
    float* WT1      = (float*)alloc(4096 * 4);
    float* WT2      = (float*)alloc(4096 * 4);
    float* dummy    = (float*)alloc((size_t)4 * 1024 * 1024);

    const int EB = (N_EDGES + 255) / 256;            // 625
    const int HB = (N_ATOMS * 16 + 255) / 256;       // 625
    const int AB = (N_ATOMS + 255) / 256;            // 40
    const int PB = (N_ATOMS * 3 + 255) / 256;        // 118
    const int SB = (N_SLOTS + 255) / 256;            // 1875

    init_kernel<<<AB, 256, 0, stream>>>(cursor, accum);
    scatter_kernel<<<EB, 256, 0, stream>>>(receivers, cursor, perm);
    pad_kernel<<<PB, 256, 0, stream>>>(cursor, edat);
    edge_geom<<<EB, 256, 0, stream>>>(positions, W_rad, senders, receivers, perm,
                                      edat, snd);
    emb_kernel<<<HB, 256, 0, stream>>>(embed, species, h0);
    transpose_winv<<<32, 256, 0, stream>>>(W_inv1, W_inv2, WT1, WT2);

    // layer 1
    gather_hs<<<SB, 256, 0, stream>>>(snd, cursor, h0, edat);
    mp_layer<<<N_ATOMS, 64, 0, stream>>>(edat, cursor, WT1, h0, h1,
                                         w_out, comp_w, species, sids, accum, 0);
    // layer 2 (energy)
    gather_hs<<<SB, 256, 0, stream>>>(snd, cursor, h1, edat);
    mp_layer<<<N_ATOMS, 64, 0, stream>>>(edat, cursor, WT2, h0, h1,
                                         w_out, comp_w, species, sids, accum, 1);

    out_kernel<<<1, 64, 0, stream>>>(accum, out);

    // ---- diagnostic probes (write only to dummy; do not affect output) ----
    probe_valu<<<2048, 256, 0, stream>>>(dummy);
    probe_wide<<<N_ATOMS, 64, 0, stream>>>(edat, dummy);
    probe_loads<<<N_ATOMS, 64, 0, stream>>>(edat, cursor, dummy);
}

// Round 13
// 318.029 us; speedup vs baseline: 1.0932x; 1.0932x over previous
//
#include <hip/hip_runtime.h>

#define N_ATOMS 10000
#define N_EDGES 160000
#define N_STRUCT 8
#define D_PAD 48             // max slots per atom; P(Poisson(16) > 48) ~ 2e-7 overall
#define EDW 48               // floats per slot: [0..15]=sh, [16..31]=R, [32..47]=hs
#define N_SLOTS (N_ATOMS * D_PAD)
#define B4 4                 // slots per register batch
#define PI_F 3.14159265358979323846f

// ---------------- setup ----------------

__global__ void init_kernel(int* __restrict__ cursor, float* __restrict__ accum) {
    int i = blockIdx.x * blockDim.x + threadIdx.x;
    if (i < N_ATOMS) cursor[i] = i * D_PAD;
    if (i < N_STRUCT) accum[i] = 0.f;
}

__global__ void scatter_kernel(const int* __restrict__ receivers, int* __restrict__ cursor,
                               int* __restrict__ perm) {
    int e = blockIdx.x * blockDim.x + threadIdx.x;
    if (e < N_EDGES) perm[e] = atomicAdd(&cursor[receivers[e]], 1);
}

// zero ONLY the pad slots [cnt, ceil4(cnt)) of each atom (all 48 floats)
__global__ void pad_kernel(const int* __restrict__ cursor, float* __restrict__ edat) {
    int i = blockIdx.x * blockDim.x + threadIdx.x;
    if (i >= N_ATOMS * 3) return;
    int a = i / 3, j = i % 3;
    int cnt = cursor[a] - a * D_PAD;
    if (cnt > D_PAD) cnt = D_PAD;
    int c4 = (cnt + B4 - 1) / B4 * B4;
    if (c4 > D_PAD) c4 = D_PAD;
    int slot = cnt + j;
    if (slot < c4) {
        float4 z = make_float4(0.f, 0.f, 0.f, 0.f);
        float4* p = (float4*)(edat + (size_t)(a * D_PAD + slot) * EDW);
        #pragma unroll
        for (int k = 0; k < 12; ++k) p[k] = z;
    }
}

__global__ void emb_kernel(const float* __restrict__ embed, const int* __restrict__ species,
                           float* __restrict__ h0) {
    int i = blockIdx.x * blockDim.x + threadIdx.x;
    if (i < N_ATOMS * 16) {
        int a = i >> 4, c = i & 15;
        h0[i] = embed[species[a] * 16 + c];
    }
}

// count-aware hs materialization: real slots only (~160K x 64 B = 10 MB)
__global__ void gather_hs(const int* __restrict__ snd, const int* __restrict__ cursor,
                          const float* __restrict__ h, float* __restrict__ edat) {
    int slot = blockIdx.x * blockDim.x + threadIdx.x;
    if (slot >= N_SLOTS) return;
    int a = slot / D_PAD, j = slot - a * D_PAD;
    int cnt = cursor[a] - a * D_PAD;
    if (cnt > D_PAD) cnt = D_PAD;
    if (j >= cnt) return;                     // pad hs already zeroed by pad_kernel
    int s = snd[slot];
    const float4* hp = (const float4*)(h + (size_t)s * 16);
    float4* ep = (float4*)(edat + (size_t)slot * EDW + 32);
    ep[0] = hp[0]; ep[1] = hp[1]; ep[2] = hp[2]; ep[3] = hp[3];
}

// transpose W_inv [256,16] -> W_invT [16,256] (both layers, one tiny launch)
__global__ void transpose_winv(const float* __restrict__ A, const float* __restrict__ B,
                               float* __restrict__ AT, float* __restrict__ BT) {
    int i = blockIdx.x * blockDim.x + threadIdx.x;
    if (i < 4096) {
        int k = i >> 4, c = i & 15;
        AT[c * 256 + k] = A[i];
    } else if (i < 8192) {
        int j = i - 4096;
        int k = j >> 4, c = j & 15;
        BT[c * 256 + k] = B[j];
    }
}

// ---------------- edge geometry -> slots ----------------

__global__ void edge_geom(const float* __restrict__ pos, const float* __restrict__ W_rad,
                          const int* __restrict__ senders, const int* __restrict__ receivers,
                          const int* __restrict__ perm,
                          float* __restrict__ edat, int* __restrict__ snd) {
    int e = blockIdx.x * blockDim.x + threadIdx.x;
    if (e >= N_EDGES) return;
    int s = senders[e], rc = receivers[e];
    int p = perm[e];
    float dx = pos[rc * 3 + 0] - pos[s * 3 + 0];
    float dy = pos[rc * 3 + 1] - pos[s * 3 + 1];
    float dz = pos[rc * 3 + 2] - pos[s * 3 + 2];
    float r = sqrtf(dx * dx + dy * dy + dz * dz);
    float rr = fmaxf(r, 1e-6f);
    float inv = 1.0f / rr;
    float x = dx * inv, y = dy * inv, z = dz * inv;
    float x2 = x * x, y2 = y * y, z2 = z * z;
    float she[16];
    she[0]  = 0.28209479f;
    she[1]  = 0.48860251f * y;
    she[2]  = 0.48860251f * z;
    she[3]  = 0.48860251f * x;
    she[4]  = 1.09254843f * x * y;
    she[5]  = 1.09254843f * y * z;
    she[6]  = 0.31539157f * (3.0f * z2 - 1.0f);
    she[7]  = 1.09254843f * x * z;
    she[8]  = 0.54627422f * (x2 - y2);
    she[9]  = 0.59004359f * y * (3.0f * x2 - y2);
    she[10] = 2.89061144f * x * y * z;
    she[11] = 0.45704579f * y * (5.0f * z2 - 1.0f);
    she[12] = 0.37317633f * z * (5.0f * z2 - 3.0f);
    she[13] = 0.45704579f * x * (5.0f * z2 - 1.0f);
    she[14] = 1.44530572f * z * (x2 - y2);
    she[15] = 0.59004359f * x * (x2 - 3.0f * y2);
    float* ed = edat + (size_t)p * EDW;
    ((float4*)ed)[0] = make_float4(she[0], she[1], she[2], she[3]);
    ((float4*)ed)[1] = make_float4(she[4], she[5], she[6], she[7]);
    ((float4*)ed)[2] = make_float4(she[8], she[9], she[10], she[11]);
    ((float4*)ed)[3] = make_float4(she[12], she[13], she[14], she[15]);
    float fc = 0.5f * (cosf(PI_F * fminf(r * 0.2f, 1.0f)) + 1.0f);
    const float c0 = 0.6324555320336759f; // sqrt(2/5)
    float bfv[8];
    #pragma unroll
    for (int n = 0; n < 8; ++n)
        bfv[n] = c0 * sinf((float)(n + 1) * PI_F * rr * 0.2f) * inv * fc;
    float Re[16];
    #pragma unroll
    for (int l = 0; l < 4; ++l) {
        #pragma unroll
        for (int n = 0; n < 4; ++n) {
            float acc = 0.0f;
            #pragma unroll
            for (int b = 0; b < 8; ++b) acc = fmaf(bfv[b], W_rad[l * 32 + b * 4 + n], acc);
            Re[l * 4 + n] = acc;
        }
    }
    ((float4*)ed)[4] = make_float4(Re[0], Re[1], Re[2], Re[3]);
    ((float4*)ed)[5] = make_float4(Re[4], Re[5], Re[6], Re[7]);
    ((float4*)ed)[6] = make_float4(Re[8], Re[9], Re[10], Re[11]);
    ((float4*)ed)[7] = make_float4(Re[12], Re[13], Re[14], Re[15]);
    snd[p] = s;
}

// ---------------- MP stage 1: accumulation only (probe_loads' fast shape) ----------------
// R12 probes: the exact hot loop without the fused epilogue runs ~20-25 us vs the
// fused kernel's 135 us. De-fuse at that boundary: this kernel is probe_loads +
// coalesced A-stores (A[atom][m][n*16+c], 16x64 floats/atom = 40 MB). No LDS, no
// branch, no epilogue.

__global__ __launch_bounds__(64, 7) void mp_accum(
    const float* __restrict__ edat,
    const int* __restrict__ cursor,
    float* __restrict__ Abuf)
{
    const int lane = threadIdx.x;                  // block = 1 wave = 1 atom
    const int atom = blockIdx.x;                   // 10000 blocks
    const int m = lane >> 2, cg = lane & 3;
    const int l = (m >= 9) ? 3 : (m >= 4) ? 2 : (m >= 1) ? 1 : 0;
    const int l4 = l * 4, cg4 = cg * 4;

    int cnt = cursor[atom] - atom * D_PAD;
    if (cnt > D_PAD) cnt = D_PAD;
    const int nb = (cnt + B4 - 1) / B4;            // real 4-slot batches (pads zeroed)

    const float* strip = edat + (size_t)atom * (D_PAD * EDW);

    float acc[4][4];  // [n][j] ; A[m][n][c=cg*4+j]
    #pragma unroll
    for (int n = 0; n < 4; ++n)
        #pragma unroll
        for (int j = 0; j < 4; ++j) acc[n][j] = 0.f;

    for (int b = 0; b < nb; ++b) {
        const float* bp = strip + b * (B4 * EDW);
        float  shv[B4];
        float4 rv[B4];
        float4 hv[B4];
        #pragma unroll
        for (int q = 0; q < B4; ++q) {
            const float* eq = bp + q * EDW;
            shv[q] = eq[m];
            rv[q]  = *(const float4*)(eq + 16 + l4);
            hv[q]  = *(const float4*)(eq + 32 + cg4);
        }
        #pragma unroll
        for (int q = 0; q < B4; ++q) {
            float hvj[4] = {hv[q].x, hv[q].y, hv[q].z, hv[q].w};
            float rvn[4] = {rv[q].x, rv[q].y, rv[q].z, rv[q].w};
            #pragma unroll
            for (int j = 0; j < 4; ++j) {
                float ww = shv[q] * hvj[j];
                #pragma unroll
                for (int n = 0; n < 4; ++n)
                    acc[n][j] = fmaf(ww, rvn[n], acc[n][j]);
            }
        }
    }

    // A[atom][m][kk], kk = n*16 + c : 4 coalesced float4 stores per lane
    float* Ap = Abuf + (size_t)atom * 1024 + m * 64 + cg4;
    #pragma unroll
    for (int n = 0; n < 4; ++n)
        *(float4*)&Ap[n * 16] =
            make_float4(acc[n][0], acc[n][1], acc[n][2], acc[n][3]);
}

// ---------------- MP stage 2: invariants + h/energy (epilogue only) ----------------
// lane L reads column L of A (16 coalesced 256B loads), computes the four l-block
// sums STATICALLY (no divergent runtime loop, compile-time scales), exchanges
// through 1 KB LDS, then the R11-verified W_invT matmul / energy reduce.

__global__ __launch_bounds__(64, 7) void mp_inv(
    const float* __restrict__ Abuf,
    const float* __restrict__ W_invT,
    const float* __restrict__ cemb, float* __restrict__ h_out,
    const float* __restrict__ w_out, const float* __restrict__ comp_w,
    const int* __restrict__ species, const int* __restrict__ sids,
    float* __restrict__ accum, int do_energy)
{
    __shared__ __attribute__((aligned(16))) float sI[256];
    const int lane = threadIdx.x;                  // block = 1 wave = 1 atom
    const int atom = blockIdx.x;

    const float* Ab = Abuf + (size_t)atom * 1024 + lane;   // column `lane`
    float v[16];
    #pragma unroll
    for (int mm = 0; mm < 16; ++mm) v[mm] = Ab[mm * 64];   // 16 coalesced loads

    float s0 = v[0] * v[0];
    float s1 = fmaf(v[3], v[3], fmaf(v[2], v[2], v[1] * v[1]));
    float s2 = fmaf(v[8], v[8], fmaf(v[7], v[7],
               fmaf(v[6], v[6], fmaf(v[5], v[5], v[4] * v[4]))));
    float s3 = fmaf(v[15], v[15], fmaf(v[14], v[14],
               fmaf(v[13], v[13], fmaf(v[12], v[12],
               fmaf(v[11], v[11], fmaf(v[10], v[10], v[9] * v[9]))))));
    const float i0 = s0;                                   // 1/sqrt(2l+1)
    const float i1 = s1 * 0.57735026918962576f;
    const float i2 = s2 * 0.44721359549995794f;
    const float i3 = s3 * 0.37796447300922720f;

    if (do_energy) {
        float e = i0 * w_out[lane] + i1 * w_out[64 + lane]
                + i2 * w_out[128 + lane] + i3 * w_out[192 + lane];
        #pragma unroll
        for (int off = 32; off > 0; off >>= 1) e += __shfl_down(e, off);
        if (lane == 0) atomicAdd(&accum[sids[atom]], e + comp_w[species[atom]]);
    } else {
        sI[lane] = i0; sI[64 + lane] = i1;
        sI[128 + lane] = i2; sI[192 + lane] = i3;          // same-wave DS in-order
        const int c = lane & 15, q4 = lane >> 4;           // lane = (c, k-quarter)
        const float* wrow = W_invT + c * 256 + q4 * 64;
        float p = 0.f;
        #pragma unroll
        for (int kk = 0; kk < 16; ++kk) {
            float4 iv = *(const float4*)&sI[q4 * 64 + kk * 4];
            float4 wv = *(const float4*)(wrow + kk * 4);
            p = fmaf(iv.x, wv.x, p);
            p = fmaf(iv.y, wv.y, p);
            p = fmaf(iv.z, wv.z, p);
            p = fmaf(iv.w, wv.w, p);
        }
        p += __shfl_xor(p, 16);
        p += __shfl_xor(p, 32);
        if (lane < 16) h_out[atom * 16 + c] = p * cemb[atom * 16 + c];
    }
}

__global__ void out_kernel(const float* __restrict__ accum, float* __restrict__ out) {
    int t = threadIdx.x;
    if (t < N_STRUCT) out[t] = accum[t];
}

// ---------------- launch ----------------

extern "C" void kernel_launch(void* const* d_in, const int* in_sizes, int n_in,
                              void* d_out, int out_size, void* d_ws, size_t ws_size,
                              hipStream_t stream) {
    const float* positions = (const float*)d_in[0];
    const float* embed     = (const float*)d_in[1];
    const float* W_rad     = (const float*)d_in[2];
    const float* W_inv1    = (const float*)d_in[3];
    const float* W_inv2    = (const float*)d_in[4];
    const float* w_out     = (const float*)d_in[5];
    const float* comp_w    = (const float*)d_in[6];
    const int* senders    = (const int*)d_in[7];
    const int* receivers  = (const int*)d_in[8];
    const int* species    = (const int*)d_in[9];
    const int* sids       = (const int*)d_in[10];
    float* out = (float*)d_out;

    char* ws = (char*)d_ws;
    size_t off = 0;
    auto alloc = [&](size_t bytes) -> void* {
        void* p = ws + off;
        off = (off + bytes + 255) & ~(size_t)255;
        return p;
    };
    float* edat     = (float*)alloc((size_t)N_SLOTS * EDW * 4);     // 92.2 MB
    float* Abuf     = (float*)alloc((size_t)N_ATOMS * 1024 * 4);    // 40.96 MB
    float* h0       = (float*)alloc((size_t)N_ATOMS * 16 * 4);
    float* h1       = (float*)alloc((size_t)N_ATOMS * 16 * 4);
    int*   cursor   = (int*)alloc((size_t)N_ATOMS * 4);
    int*   perm     = (int*)alloc((size_t)N_EDGES * 4);
    int*   snd      = (int*)alloc((size_t)N_SLOTS * 4);
    float* accum    = (float*)alloc(8 * 4);
    float* WT1      = (float*)alloc(4096 * 4);
    float* WT2      = (float*)alloc(4096 * 4);

    const int EB = (N_EDGES + 255) / 256;            // 625
    const int HB = (N_ATOMS * 16 + 255) / 256;       // 625
    const int AB = (N_ATOMS + 255) / 256;            // 40
    const int PB = (N_ATOMS * 3 + 255) / 256;        // 118
    const int SB = (N_SLOTS + 255) / 256;            // 1875

    init_kernel<<<AB, 256, 0, stream>>>(cursor, accum);
    scatter_kernel<<<EB, 256, 0, stream>>>(receivers, cursor, perm);
    pad_kernel<<<PB, 256, 0, stream>>>(cursor, edat);
    edge_geom<<<EB, 256, 0, stream>>>(positions, W_rad, senders, receivers, perm,
                                      edat, snd);
    emb_kernel<<<HB, 256, 0, stream>>>(embed, species, h0);
    transpose_winv<<<32, 256, 0, stream>>>(W_inv1, W_inv2, WT1, WT2);

    // layer 1
    gather_hs<<<SB, 256, 0, stream>>>(snd, cursor, h0, edat);
    mp_accum<<<N_ATOMS, 64, 0, stream>>>(edat, cursor, Abuf);
    mp_inv<<<N_ATOMS, 64, 0, stream>>>(Abuf, WT1, h0, h1,
                                       w_out, comp_w, species, sids, accum, 0);
    // layer 2 (energy)
    gather_hs<<<SB, 256, 0, stream>>>(snd, cursor, h1, edat);
    mp_accum<<<N_ATOMS, 64, 0, stream>>>(edat, cursor, Abuf);
    mp_inv<<<N_ATOMS, 64, 0, stream>>>(Abuf, WT2, h0, h1,
                                       w_out, comp_w, species, sids, accum, 1);

    out_kernel<<<1, 64, 0, stream>>>(accum, out);
}

// Round 14
// 184.421 us; speedup vs baseline: 1.8852x; 1.7245x over previous
//
#include <hip/hip_runtime.h>

#define N_ATOMS 10000
#define N_EDGES 160000
#define N_STRUCT 8
#define D_PAD 48             // max slots per atom; P(Poisson(16) > 48) ~ 2e-7 overall
#define EDW 48               // floats per slot: [0..15]=sh, [16..31]=R, [32..47]=hs
#define N_SLOTS (N_ATOMS * D_PAD)
#define B4 4                 // slots per register batch
#define PI_F 3.14159265358979323846f

// ---------------- setup ----------------

__global__ void init_kernel(int* __restrict__ cursor, float* __restrict__ accum) {
    int i = blockIdx.x * blockDim.x + threadIdx.x;
    if (i < N_ATOMS) cursor[i] = i * D_PAD;
    if (i < N_STRUCT) accum[i] = 0.f;
}

__global__ void scatter_kernel(const int* __restrict__ receivers, int* __restrict__ cursor,
                               int* __restrict__ perm) {
    int e = blockIdx.x * blockDim.x + threadIdx.x;
    if (e < N_EDGES) perm[e] = atomicAdd(&cursor[receivers[e]], 1);
}

// zero ONLY the pad slots [cnt, ceil4(cnt)) of each atom (all 48 floats)
__global__ void pad_kernel(const int* __restrict__ cursor, float* __restrict__ edat) {
    int i = blockIdx.x * blockDim.x + threadIdx.x;
    if (i >= N_ATOMS * 3) return;
    int a = i / 3, j = i % 3;
    int cnt = cursor[a] - a * D_PAD;
    if (cnt > D_PAD) cnt = D_PAD;
    int c4 = (cnt + B4 - 1) / B4 * B4;
    if (c4 > D_PAD) c4 = D_PAD;
    int slot = cnt + j;
    if (slot < c4) {
        float4 z = make_float4(0.f, 0.f, 0.f, 0.f);
        float4* p = (float4*)(edat + (size_t)(a * D_PAD + slot) * EDW);
        #pragma unroll
        for (int k = 0; k < 12; ++k) p[k] = z;
    }
}

__global__ void emb_kernel(const float* __restrict__ embed, const int* __restrict__ species,
                           float* __restrict__ h0) {
    int i = blockIdx.x * blockDim.x + threadIdx.x;
    if (i < N_ATOMS * 16) {
        int a = i >> 4, c = i & 15;
        h0[i] = embed[species[a] * 16 + c];
    }
}

// count-aware hs materialization: real slots only (~160K x 64 B = 10 MB)
__global__ void gather_hs(const int* __restrict__ snd, const int* __restrict__ cursor,
                          const float* __restrict__ h, float* __restrict__ edat) {
    int slot = blockIdx.x * blockDim.x + threadIdx.x;
    if (slot >= N_SLOTS) return;
    int a = slot / D_PAD, j = slot - a * D_PAD;
    int cnt = cursor[a] - a * D_PAD;
    if (cnt > D_PAD) cnt = D_PAD;
    if (j >= cnt) return;                     // pad hs already zeroed by pad_kernel
    int s = snd[slot];
    const float4* hp = (const float4*)(h + (size_t)s * 16);
    float4* ep = (float4*)(edat + (size_t)slot * EDW + 32);
    ep[0] = hp[0]; ep[1] = hp[1]; ep[2] = hp[2]; ep[3] = hp[3];
}

// transpose W_inv [256,16] -> W_invT [16,256] (both layers, one tiny launch)
__global__ void transpose_winv(const float* __restrict__ A, const float* __restrict__ B,
                               float* __restrict__ AT, float* __restrict__ BT) {
    int i = blockIdx.x * blockDim.x + threadIdx.x;
    if (i < 4096) {
        int k = i >> 4, c = i & 15;
        AT[c * 256 + k] = A[i];
    } else if (i < 8192) {
        int j = i - 4096;
        int k = j >> 4, c = j & 15;
        BT[c * 256 + k] = B[j];
    }
}

// ---------------- edge geometry -> slots ----------------

__global__ void edge_geom(const float* __restrict__ pos, const float* __restrict__ W_rad,
                          const int* __restrict__ senders, const int* __restrict__ receivers,
                          const int* __restrict__ perm,
                          float* __restrict__ edat, int* __restrict__ snd) {
    int e = blockIdx.x * blockDim.x + threadIdx.x;
    if (e >= N_EDGES) return;
    int s = senders[e], rc = receivers[e];
    int p = perm[e];
    float dx = pos[rc * 3 + 0] - pos[s * 3 + 0];
    float dy = pos[rc * 3 + 1] - pos[s * 3 + 1];
    float dz = pos[rc * 3 + 2] - pos[s * 3 + 2];
    float r = sqrtf(dx * dx + dy * dy + dz * dz);
    float rr = fmaxf(r, 1e-6f);
    float inv = 1.0f / rr;
    float x = dx * inv, y = dy * inv, z = dz * inv;
    float x2 = x * x, y2 = y * y, z2 = z * z;
    float she[16];
    she[0]  = 0.28209479f;
    she[1]  = 0.48860251f * y;
    she[2]  = 0.48860251f * z;
    she[3]  = 0.48860251f * x;
    she[4]  = 1.09254843f * x * y;
    she[5]  = 1.09254843f * y * z;
    she[6]  = 0.31539157f * (3.0f * z2 - 1.0f);
    she[7]  = 1.09254843f * x * z;
    she[8]  = 0.54627422f * (x2 - y2);
    she[9]  = 0.59004359f * y * (3.0f * x2 - y2);
    she[10] = 2.89061144f * x * y * z;
    she[11] = 0.45704579f * y * (5.0f * z2 - 1.0f);
    she[12] = 0.37317633f * z * (5.0f * z2 - 3.0f);
    she[13] = 0.45704579f * x * (5.0f * z2 - 1.0f);
    she[14] = 1.44530572f * z * (x2 - y2);
    she[15] = 0.59004359f * x * (x2 - 3.0f * y2);
    float* ed = edat + (size_t)p * EDW;
    ((float4*)ed)[0] = make_float4(she[0], she[1], she[2], she[3]);
    ((float4*)ed)[1] = make_float4(she[4], she[5], she[6], she[7]);
    ((float4*)ed)[2] = make_float4(she[8], she[9], she[10], she[11]);
    ((float4*)ed)[3] = make_float4(she[12], she[13], she[14], she[15]);
    float fc = 0.5f * (cosf(PI_F * fminf(r * 0.2f, 1.0f)) + 1.0f);
    const float c0 = 0.6324555320336759f; // sqrt(2/5)
    float bfv[8];
    #pragma unroll
    for (int n = 0; n < 8; ++n)
        bfv[n] = c0 * sinf((float)(n + 1) * PI_F * rr * 0.2f) * inv * fc;
    float Re[16];
    #pragma unroll
    for (int l = 0; l < 4; ++l) {
        #pragma unroll
        for (int n = 0; n < 4; ++n) {
            float acc = 0.0f;
            #pragma unroll
            for (int b = 0; b < 8; ++b) acc = fmaf(bfv[b], W_rad[l * 32 + b * 4 + n], acc);
            Re[l * 4 + n] = acc;
        }
    }
    ((float4*)ed)[4] = make_float4(Re[0], Re[1], Re[2], Re[3]);
    ((float4*)ed)[5] = make_float4(Re[4], Re[5], Re[6], Re[7]);
    ((float4*)ed)[6] = make_float4(Re[8], Re[9], Re[10], Re[11]);
    ((float4*)ed)[7] = make_float4(Re[12], Re[13], Re[14], Re[15]);
    snd[p] = s;
}

// ---------------- MP stage 1: accumulation only (PROVEN ~11 us, unchanged) ----------------

__global__ __launch_bounds__(64, 7) void mp_accum(
    const float* __restrict__ edat,
    const int* __restrict__ cursor,
    float* __restrict__ Abuf)
{
    const int lane = threadIdx.x;                  // block = 1 wave = 1 atom
    const int atom = blockIdx.x;                   // 10000 blocks
    const int m = lane >> 2, cg = lane & 3;
    const int l = (m >= 9) ? 3 : (m >= 4) ? 2 : (m >= 1) ? 1 : 0;
    const int l4 = l * 4, cg4 = cg * 4;

    int cnt = cursor[atom] - atom * D_PAD;
    if (cnt > D_PAD) cnt = D_PAD;
    const int nb = (cnt + B4 - 1) / B4;            // real 4-slot batches (pads zeroed)

    const float* strip = edat + (size_t)atom * (D_PAD * EDW);

    float acc[4][4];  // [n][j] ; A[m][n][c=cg*4+j]
    #pragma unroll
    for (int n = 0; n < 4; ++n)
        #pragma unroll
        for (int j = 0; j < 4; ++j) acc[n][j] = 0.f;

    for (int b = 0; b < nb; ++b) {
        const float* bp = strip + b * (B4 * EDW);
        float  shv[B4];
        float4 rv[B4];
        float4 hv[B4];
        #pragma unroll
        for (int q = 0; q < B4; ++q) {
            const float* eq = bp + q * EDW;
            shv[q] = eq[m];
            rv[q]  = *(const float4*)(eq + 16 + l4);
            hv[q]  = *(const float4*)(eq + 32 + cg4);
        }
        #pragma unroll
        for (int q = 0; q < B4; ++q) {
            float hvj[4] = {hv[q].x, hv[q].y, hv[q].z, hv[q].w};
            float rvn[4] = {rv[q].x, rv[q].y, rv[q].z, rv[q].w};
            #pragma unroll
            for (int j = 0; j < 4; ++j) {
                float ww = shv[q] * hvj[j];
                #pragma unroll
                for (int n = 0; n < 4; ++n)
                    acc[n][j] = fmaf(ww, rvn[n], acc[n][j]);
            }
        }
    }

    // A[atom][m][kk], kk = n*16 + c : 4 coalesced float4 stores per lane
    float* Ap = Abuf + (size_t)atom * 1024 + m * 64 + cg4;
    #pragma unroll
    for (int n = 0; n < 4; ++n)
        *(float4*)&Ap[n * 16] =
            make_float4(acc[n][0], acc[n][1], acc[n][2], acc[n][3]);
}

// ---------------- MP stage 2 REWRITTEN: dense 16-atom blocks, all coalesced ----------------
// R13: the trivial per-wave epilogue kernel inherited the full 133us wall (VALU
// 0.68%!) while the heavy mp_accum ran in 11us. Rewrite the epilogue in the fast
// kernel's idiom: 256-thread blocks x 16 atoms, linear float4 Abuf streams,
// LDS-broadcast matmul (no scattered W gathers, no shfl in h path), full-line
// coalesced h stores, run-compressed atomics.

#define SROW 260   // padded row stride (floats) for sInv/sWT: bank-spread + f4-aligned

__global__ __launch_bounds__(256, 2) void mp_inv2(
    const float* __restrict__ Abuf,
    const float* __restrict__ W_invT,
    const float* __restrict__ cemb, float* __restrict__ h_out,
    const float* __restrict__ w_out, const float* __restrict__ comp_w,
    const int* __restrict__ species, const int* __restrict__ sids,
    float* __restrict__ accum, int do_energy)
{
    __shared__ __attribute__((aligned(16))) float sWT[16 * SROW];  // W_invT rows (h path)
    __shared__ __attribute__((aligned(16))) float sInv[16 * SROW]; // inv per atom (h path)
    __shared__ __attribute__((aligned(16))) float sTmp[4][1024];   // wave-private squares
    __shared__ float sE[16];                                       // per-atom energy

    const int t = threadIdx.x;
    const int w = t >> 6, lane = t & 63;
    const int blk = blockIdx.x;                    // 625 blocks x 16 atoms

    if (!do_energy) {
        #pragma unroll
        for (int i = 0; i < 16; ++i) {             // coalesced W_invT -> sWT
            int idx = i * 256 + t;
            sWT[(idx >> 8) * SROW + (idx & 255)] = W_invT[idx];
        }
    }

    // ---- per 4-atom group: squares -> sTmp (wave-private) -> inv ----
    const float4* A4 = (const float4*)Abuf;
    #pragma unroll
    for (int g = 0; g < 4; ++g) {
        const int atomL = g * 4 + w;               // wave w owns atom g*4+w
        const int atom = blk * 16 + atomL;
        #pragma unroll
        for (int i = 0; i < 4; ++i) {
            float4 v = A4[(size_t)atom * 256 + i * 64 + lane];   // coalesced 1KB
            *(float4*)&sTmp[w][(i * 64 + lane) * 4] =
                make_float4(v.x * v.x, v.y * v.y, v.z * v.z, v.w * v.w);
        }
        // same-wave DS in-order: read columns k = lane
        const float* T = &sTmp[w][0];
        const int k = lane;
        float s0 = T[k];
        float s1 = T[64 + k] + T[128 + k] + T[192 + k];
        float s2 = T[256 + k] + T[320 + k] + T[384 + k] + T[448 + k] + T[512 + k];
        float s3 = T[576 + k] + T[640 + k] + T[704 + k] + T[768 + k]
                 + T[832 + k] + T[896 + k] + T[960 + k];
        const float i0 = s0;
        const float i1 = s1 * 0.57735026918962576f;
        const float i2 = s2 * 0.44721359549995794f;
        const float i3 = s3 * 0.37796447300922720f;

        if (do_energy) {
            float pe = i0 * w_out[k] + i1 * w_out[64 + k]
                     + i2 * w_out[128 + k] + i3 * w_out[192 + k];
            #pragma unroll
            for (int off = 32; off > 0; off >>= 1) pe += __shfl_down(pe, off);
            if (lane == 0) sE[atomL] = pe;
        } else {
            float* si = &sInv[atomL * SROW];
            si[k] = i0; si[64 + k] = i1; si[128 + k] = i2; si[192 + k] = i3;
        }
    }
    __syncthreads();

    if (do_energy) {
        if (t == 0) {                              // run-compressed atomics (sids sorted)
            const int base = blk * 16;
            int cursid = sids[base];
            float run = 0.f;
            for (int a = 0; a < 16; ++a) {
                int sid = sids[base + a];
                float e = sE[a] + comp_w[species[base + a]];
                if (sid != cursid) { atomicAdd(&accum[cursid], run); run = 0.f; cursid = sid; }
                run += e;
            }
            atomicAdd(&accum[cursid], run);
        }
    } else {
        // h[a][c] = (sum_k inv[a][k] * W[k][c]) * cemb : LDS-broadcast GEMM
        const int aL = t >> 4, c = t & 15;
        const float* ivp = &sInv[aL * SROW];
        const float* wvp = &sWT[c * SROW];
        float p = 0.f;
        #pragma unroll
        for (int kk = 0; kk < 64; ++kk) {
            float4 iv = *(const float4*)&ivp[kk * 4];
            float4 wv = *(const float4*)&wvp[kk * 4];
            p = fmaf(iv.x, wv.x, p);
            p = fmaf(iv.y, wv.y, p);
            p = fmaf(iv.z, wv.z, p);
            p = fmaf(iv.w, wv.w, p);
        }
        const int gi = blk * 256 + t;              // = atom*16 + c : full-line store
        h_out[gi] = p * cemb[gi];
    }
}

__global__ void out_kernel(const float* __restrict__ accum, float* __restrict__ out) {
    int t = threadIdx.x;
    if (t < N_STRUCT) out[t] = accum[t];
}

// ---------------- launch ----------------

extern "C" void kernel_launch(void* const* d_in, const int* in_sizes, int n_in,
                              void* d_out, int out_size, void* d_ws, size_t ws_size,
                              hipStream_t stream) {
    const float* positions = (const float*)d_in[0];
    const float* embed     = (const float*)d_in[1];
    const float* W_rad     = (const float*)d_in[2];
    const float* W_inv1    = (const float*)d_in[3];
    const float* W_inv2    = (const float*)d_in[4];
    const float* w_out     = (const float*)d_in[5];
    const float* comp_w    = (const float*)d_in[6];
    const int* senders    = (const int*)d_in[7];
    const int* receivers  = (const int*)d_in[8];
    const int* species    = (const int*)d_in[9];
    const int* sids       = (const int*)d_in[10];
    float* out = (float*)d_out;

    char* ws = (char*)d_ws;
    size_t off = 0;
    auto alloc = [&](size_t bytes) -> void* {
        void* p = ws + off;
        off = (off + bytes + 255) & ~(size_t)255;
        return p;
    };
    float* edat     = (float*)alloc((size_t)N_SLOTS * EDW * 4);     // 92.2 MB
    float* Abuf     = (float*)alloc((size_t)N_ATOMS * 1024 * 4);    // 40.96 MB
    float* h0       = (float*)alloc((size_t)N_ATOMS * 16 * 4);
    float* h1       = (float*)alloc((size_t)N_ATOMS * 16 * 4);
    int*   cursor   = (int*)alloc((size_t)N_ATOMS * 4);
    int*   perm     = (int*)alloc((size_t)N_EDGES * 4);
    int*   snd      = (int*)alloc((size_t)N_SLOTS * 4);
    float* accum    = (float*)alloc(8 * 4);
    float* WT1      = (float*)alloc(4096 * 4);
    float* WT2      = (float*)alloc(4096 * 4);

    const int EB = (N_EDGES + 255) / 256;            // 625
    const int HB = (N_ATOMS * 16 + 255) / 256;       // 625
    const int AB = (N_ATOMS + 255) / 256;            // 40
    const int PB = (N_ATOMS * 3 + 255) / 256;        // 118
    const int SB = (N_SLOTS + 255) / 256;            // 1875

    init_kernel<<<AB, 256, 0, stream>>>(cursor, accum);
    scatter_kernel<<<EB, 256, 0, stream>>>(receivers, cursor, perm);
    pad_kernel<<<PB, 256, 0, stream>>>(cursor, edat);
    edge_geom<<<EB, 256, 0, stream>>>(positions, W_rad, senders, receivers, perm,
                                      edat, snd);
    emb_kernel<<<HB, 256, 0, stream>>>(embed, species, h0);
    transpose_winv<<<32, 256, 0, stream>>>(W_inv1, W_inv2, WT1, WT2);

    // layer 1
    gather_hs<<<SB, 256, 0, stream>>>(snd, cursor, h0, edat);
    mp_accum<<<N_ATOMS, 64, 0, stream>>>(edat, cursor, Abuf);
    mp_inv2<<<N_ATOMS / 16, 256, 0, stream>>>(Abuf, WT1, h0, h1,
                                              w_out, comp_w, species, sids, accum, 0);
    // layer 2 (energy)
    gather_hs<<<SB, 256, 0, stream>>>(snd, cursor, h1, edat);
    mp_accum<<<N_ATOMS, 64, 0, stream>>>(edat, cursor, Abuf);
    mp_inv2<<<N_ATOMS / 16, 256, 0, stream>>>(Abuf, WT2, h0, h1,
                                              w_out, comp_w, species, sids, accum, 1);

    out_kernel<<<1, 64, 0, stream>>>(accum, out);
}

// Round 15
// 161.839 us; speedup vs baseline: 2.1482x; 1.1395x over previous
//
#include <hip/hip_runtime.h>

#define N_ATOMS 10000
#define N_EDGES 160000
#define N_STRUCT 8
#define D_PAD 48             // max slots per atom; P(Poisson(16) > 48) ~ 2e-7 overall
#define EDW 32               // floats per slot: [0..15]=sh, [16..31]=R (h gathered live)
#define N_SLOTS (N_ATOMS * D_PAD)
#define B4 4                 // slots per register batch
#define PI_F 3.14159265358979323846f
#define SROW 260             // padded LDS row stride (floats)

// ---------------- setup ----------------

__global__ void init_kernel(int* __restrict__ cursor, float* __restrict__ accum) {
    int i = blockIdx.x * blockDim.x + threadIdx.x;
    if (i < N_ATOMS) cursor[i] = i * D_PAD;
    if (i < N_STRUCT) accum[i] = 0.f;
}

__global__ void scatter_kernel(const int* __restrict__ receivers, int* __restrict__ cursor,
                               int* __restrict__ perm) {
    int e = blockIdx.x * blockDim.x + threadIdx.x;
    if (e < N_EDGES) perm[e] = atomicAdd(&cursor[receivers[e]], 1);
}

// zero ONLY the pad slots [cnt, ceil4(cnt)) of each atom + their snd index
// (snd must be valid: shv=0 kills finite garbage but not NaN from wild reads)
__global__ void pad_kernel(const int* __restrict__ cursor, float* __restrict__ edat,
                           int* __restrict__ snd) {
    int i = blockIdx.x * blockDim.x + threadIdx.x;
    if (i >= N_ATOMS * 3) return;
    int a = i / 3, j = i % 3;
    int cnt = cursor[a] - a * D_PAD;
    if (cnt > D_PAD) cnt = D_PAD;
    int c4 = (cnt + B4 - 1) / B4 * B4;
    if (c4 > D_PAD) c4 = D_PAD;
    int slot = cnt + j;
    if (slot < c4) {
        float4 z = make_float4(0.f, 0.f, 0.f, 0.f);
        float4* p = (float4*)(edat + (size_t)(a * D_PAD + slot) * EDW);
        #pragma unroll
        for (int k = 0; k < 8; ++k) p[k] = z;
        snd[a * D_PAD + slot] = 0;
    }
}

__global__ void emb_kernel(const float* __restrict__ embed, const int* __restrict__ species,
                           float* __restrict__ h0) {
    int i = blockIdx.x * blockDim.x + threadIdx.x;
    if (i < N_ATOMS * 16) {
        int a = i >> 4, c = i & 15;
        h0[i] = embed[species[a] * 16 + c];
    }
}

// transpose W_inv [256,16] -> W_invT [16,256] (both layers, one tiny launch)
__global__ void transpose_winv(const float* __restrict__ A, const float* __restrict__ B,
                               float* __restrict__ AT, float* __restrict__ BT) {
    int i = blockIdx.x * blockDim.x + threadIdx.x;
    if (i < 4096) {
        int k = i >> 4, c = i & 15;
        AT[c * 256 + k] = A[i];
    } else if (i < 8192) {
        int j = i - 4096;
        int k = j >> 4, c = j & 15;
        BT[c * 256 + k] = B[j];
    }
}

// ---------------- edge geometry -> slots (sh + R only, 128 B/slot) ----------------

__global__ void edge_geom(const float* __restrict__ pos, const float* __restrict__ W_rad,
                          const int* __restrict__ senders, const int* __restrict__ receivers,
                          const int* __restrict__ perm,
                          float* __restrict__ edat, int* __restrict__ snd) {
    int e = blockIdx.x * blockDim.x + threadIdx.x;
    if (e >= N_EDGES) return;
    int s = senders[e], rc = receivers[e];
    int p = perm[e];
    float dx = pos[rc * 3 + 0] - pos[s * 3 + 0];
    float dy = pos[rc * 3 + 1] - pos[s * 3 + 1];
    float dz = pos[rc * 3 + 2] - pos[s * 3 + 2];
    float r = sqrtf(dx * dx + dy * dy + dz * dz);
    float rr = fmaxf(r, 1e-6f);
    float inv = 1.0f / rr;
    float x = dx * inv, y = dy * inv, z = dz * inv;
    float x2 = x * x, y2 = y * y, z2 = z * z;
    float she[16];
    she[0]  = 0.28209479f;
    she[1]  = 0.48860251f * y;
    she[2]  = 0.48860251f * z;
    she[3]  = 0.48860251f * x;
    she[4]  = 1.09254843f * x * y;
    she[5]  = 1.09254843f * y * z;
    she[6]  = 0.31539157f * (3.0f * z2 - 1.0f);
    she[7]  = 1.09254843f * x * z;
    she[8]  = 0.54627422f * (x2 - y2);
    she[9]  = 0.59004359f * y * (3.0f * x2 - y2);
    she[10] = 2.89061144f * x * y * z;
    she[11] = 0.45704579f * y * (5.0f * z2 - 1.0f);
    she[12] = 0.37317633f * z * (5.0f * z2 - 3.0f);
    she[13] = 0.45704579f * x * (5.0f * z2 - 1.0f);
    she[14] = 1.44530572f * z * (x2 - y2);
    she[15] = 0.59004359f * x * (x2 - 3.0f * y2);
    float* ed = edat + (size_t)p * EDW;
    ((float4*)ed)[0] = make_float4(she[0], she[1], she[2], she[3]);
    ((float4*)ed)[1] = make_float4(she[4], she[5], she[6], she[7]);
    ((float4*)ed)[2] = make_float4(she[8], she[9], she[10], she[11]);
    ((float4*)ed)[3] = make_float4(she[12], she[13], she[14], she[15]);
    float fc = 0.5f * (cosf(PI_F * fminf(r * 0.2f, 1.0f)) + 1.0f);
    const float c0 = 0.6324555320336759f; // sqrt(2/5)
    float bfv[8];
    #pragma unroll
    for (int n = 0; n < 8; ++n)
        bfv[n] = c0 * sinf((float)(n + 1) * PI_F * rr * 0.2f) * inv * fc;
    float Re[16];
    #pragma unroll
    for (int l = 0; l < 4; ++l) {
        #pragma unroll
        for (int n = 0; n < 4; ++n) {
            float acc = 0.0f;
            #pragma unroll
            for (int b = 0; b < 8; ++b) acc = fmaf(bfv[b], W_rad[l * 32 + b * 4 + n], acc);
            Re[l * 4 + n] = acc;
        }
    }
    ((float4*)ed)[4] = make_float4(Re[0], Re[1], Re[2], Re[3]);
    ((float4*)ed)[5] = make_float4(Re[4], Re[5], Re[6], Re[7]);
    ((float4*)ed)[6] = make_float4(Re[8], Re[9], Re[10], Re[11]);
    ((float4*)ed)[7] = make_float4(Re[12], Re[13], Re[14], Re[15]);
    snd[p] = s;
}

// ---------------- MP stage 1: accum + live h gather + inv (fast idioms only) ----------------
// Proven 64-thread accum loop (R12-probe ~11us) + R7's proven shfl-broadcast live h
// gather (kills gather_hs + 16 floats/slot of edat) + mp_inv2's PROVEN static
// column-sum idiom on 4KB LDS. Output = inv only (256 floats/atom, 10 MB) --
// replaces the 41 MB Abuf round-trip.

__global__ __launch_bounds__(64, 7) void mp_accum2(
    const float* __restrict__ edat, const int* __restrict__ snd,
    const int* __restrict__ cursor, const float* __restrict__ h_in,
    float* __restrict__ Inv)
{
    __shared__ __attribute__((aligned(16))) float wl[1024];   // squares [m*64 + k]
    const int lane = threadIdx.x;                  // block = 1 wave = 1 atom
    const int atom = blockIdx.x;                   // 10000 blocks
    const int m = lane >> 2, cg = lane & 3;
    const int l = (m >= 9) ? 3 : (m >= 4) ? 2 : (m >= 1) ? 1 : 0;
    const int l4 = l * 4, cg4 = cg * 4;

    int cnt = cursor[atom] - atom * D_PAD;
    if (cnt > D_PAD) cnt = D_PAD;
    const int nb = (cnt + B4 - 1) / B4;            // real 4-slot batches (pads zeroed)

    int sv = 0;
    if (lane < D_PAD) sv = snd[atom * D_PAD + lane];

    const float* strip = edat + (size_t)atom * (D_PAD * EDW);

    float acc[4][4];  // [n][j] ; A[m][n*16 + cg*4+j]
    #pragma unroll
    for (int n = 0; n < 4; ++n)
        #pragma unroll
        for (int j = 0; j < 4; ++j) acc[n][j] = 0.f;

    for (int b = 0; b < nb; ++b) {
        const int s0 = b * B4;
        const float* bp = strip + s0 * EDW;
        float  shv[B4];
        float4 rv[B4];
        float4 hv[B4];
        #pragma unroll
        for (int q = 0; q < B4; ++q) {
            const float* eq = bp + q * EDW;
            shv[q] = eq[m];
            rv[q]  = *(const float4*)(eq + 16 + l4);
            hv[q]  = *(const float4*)(h_in + (size_t)__shfl(sv, s0 + q) * 16 + cg4);
        }
        #pragma unroll
        for (int q = 0; q < B4; ++q) {
            float hvj[4] = {hv[q].x, hv[q].y, hv[q].z, hv[q].w};
            float rvn[4] = {rv[q].x, rv[q].y, rv[q].z, rv[q].w};
            #pragma unroll
            for (int j = 0; j < 4; ++j) {
                float ww = shv[q] * hvj[j];
                #pragma unroll
                for (int n = 0; n < 4; ++n)
                    acc[n][j] = fmaf(ww, rvn[n], acc[n][j]);
            }
        }
    }

    // squares -> LDS (same-wave DS is in-order; k = n*16+c in [0,64))
    #pragma unroll
    for (int n = 0; n < 4; ++n)
        *(float4*)&wl[m * 64 + n * 16 + cg4] =
            make_float4(acc[n][0] * acc[n][0], acc[n][1] * acc[n][1],
                        acc[n][2] * acc[n][2], acc[n][3] * acc[n][3]);

    // STATIC column sums (mp_inv2's verified idiom): lane = k
    const float* T = wl;
    const int k = lane;
    float s0v = T[k];
    float s1v = T[64 + k] + T[128 + k] + T[192 + k];
    float s2v = T[256 + k] + T[320 + k] + T[384 + k] + T[448 + k] + T[512 + k];
    float s3v = T[576 + k] + T[640 + k] + T[704 + k] + T[768 + k]
              + T[832 + k] + T[896 + k] + T[960 + k];
    float* ip = Inv + (size_t)atom * 256;
    ip[k]       = s0v;
    ip[64 + k]  = s1v * 0.57735026918962576f;
    ip[128 + k] = s2v * 0.44721359549995794f;
    ip[192 + k] = s3v * 0.37796447300922720f;
}

// ---------------- MP stage 2: h / energy from inv (dense idiom, proven) ----------------

__global__ __launch_bounds__(256, 2) void mp_inv3(
    const float* __restrict__ Inv,
    const float* __restrict__ W_invT,
    const float* __restrict__ cemb, float* __restrict__ h_out,
    const float* __restrict__ w_out, const float* __restrict__ comp_w,
    const int* __restrict__ species, const int* __restrict__ sids,
    float* __restrict__ accum, int do_energy)
{
    __shared__ __attribute__((aligned(16))) float sWT[16 * SROW];
    __shared__ __attribute__((aligned(16))) float sInv[16 * SROW];
    __shared__ float sE[16];
    const int t = threadIdx.x;
    const int w = t >> 6, lane = t & 63;
    const int blk = blockIdx.x;                    // 625 blocks x 16 atoms

    if (do_energy) {
        #pragma unroll
        for (int g = 0; g < 4; ++g) {
            const int atomL = g * 4 + w;
            const size_t base = (size_t)(blk * 16 + atomL) * 256;
            float i0 = Inv[base + lane];
            float i1 = Inv[base + 64 + lane];
            float i2 = Inv[base + 128 + lane];
            float i3 = Inv[base + 192 + lane];
            float pe = i0 * w_out[lane] + i1 * w_out[64 + lane]
                     + i2 * w_out[128 + lane] + i3 * w_out[192 + lane];
            #pragma unroll
            for (int off = 32; off > 0; off >>= 1) pe += __shfl_down(pe, off);
            if (lane == 0) sE[atomL] = pe;
        }
        __syncthreads();
        if (t == 0) {                              // run-compressed atomics (sids sorted)
            const int base = blk * 16;
            int cursid = sids[base];
            float run = 0.f;
            for (int a = 0; a < 16; ++a) {
                int sid = sids[base + a];
                float e = sE[a] + comp_w[species[base + a]];
                if (sid != cursid) { atomicAdd(&accum[cursid], run); run = 0.f; cursid = sid; }
                run += e;
            }
            atomicAdd(&accum[cursid], run);
        }
    } else {
        #pragma unroll
        for (int i = 0; i < 16; ++i) {             // coalesced loads -> LDS
            int idx = i * 256 + t;
            int row = idx >> 8, col = idx & 255;
            sWT[row * SROW + col]  = W_invT[idx];
            sInv[row * SROW + col] = Inv[(size_t)blk * 4096 + idx];
        }
        __syncthreads();
        // h[a][c] = (sum_k inv[a][k] * W[k][c]) * cemb : LDS-broadcast GEMM
        const int aL = t >> 4, c = t & 15;
        const float* ivp = &sInv[aL * SROW];
        const float* wvp = &sWT[c * SROW];
        float p = 0.f;
        #pragma unroll
        for (int kk = 0; kk < 64; ++kk) {
            float4 iv = *(const float4*)&ivp[kk * 4];
            float4 wv = *(const float4*)&wvp[kk * 4];
            p = fmaf(iv.x, wv.x, p);
            p = fmaf(iv.y, wv.y, p);
            p = fmaf(iv.z, wv.z, p);
            p = fmaf(iv.w, wv.w, p);
        }
        const int gi = blk * 256 + t;              // = atom*16 + c : full-line store
        h_out[gi] = p * cemb[gi];
    }
}

__global__ void out_kernel(const float* __restrict__ accum, float* __restrict__ out) {
    int t = threadIdx.x;
    if (t < N_STRUCT) out[t] = accum[t];
}

// ---------------- launch ----------------

extern "C" void kernel_launch(void* const* d_in, const int* in_sizes, int n_in,
                              void* d_out, int out_size, void* d_ws, size_t ws_size,
                              hipStream_t stream) {
    const float* positions = (const float*)d_in[0];
    const float* embed     = (const float*)d_in[1];
    const float* W_rad     = (const float*)d_in[2];
    const float* W_inv1    = (const float*)d_in[3];
    const float* W_inv2    = (const float*)d_in[4];
    const float* w_out     = (const float*)d_in[5];
    const float* comp_w    = (const float*)d_in[6];
    const int* senders    = (const int*)d_in[7];
    const int* receivers  = (const int*)d_in[8];
    const int* species    = (const int*)d_in[9];
    const int* sids       = (const int*)d_in[10];
    float* out = (float*)d_out;

    char* ws = (char*)d_ws;
    size_t off = 0;
    auto alloc = [&](size_t bytes) -> void* {
        void* p = ws + off;
        off = (off + bytes + 255) & ~(size_t)255;
        return p;
    };
    float* edat     = (float*)alloc((size_t)N_SLOTS * EDW * 4);     // 61.4 MB
    float* Inv      = (float*)alloc((size_t)N_ATOMS * 256 * 4);     // 10.24 MB
    float* h0       = (float*)alloc((size_t)N_ATOMS * 16 * 4);
    float* h1       = (float*)alloc((size_t)N_ATOMS * 16 * 4);
    int*   cursor   = (int*)alloc((size_t)N_ATOMS * 4);
    int*   perm     = (int*)alloc((size_t)N_EDGES * 4);
    int*   snd      = (int*)alloc((size_t)N_SLOTS * 4);
    float* accum    = (float*)alloc(8 * 4);
    float* WT1      = (float*)alloc(4096 * 4);
    float* WT2      = (float*)alloc(4096 * 4);

    const int EB = (N_EDGES + 255) / 256;            // 625
    const int HB = (N_ATOMS * 16 + 255) / 256;       // 625
    const int AB = (N_ATOMS + 255) / 256;            // 40
    const int PB = (N_ATOMS * 3 + 255) / 256;        // 118

    init_kernel<<<AB, 256, 0, stream>>>(cursor, accum);
    scatter_kernel<<<EB, 256, 0, stream>>>(receivers, cursor, perm);
    pad_kernel<<<PB, 256, 0, stream>>>(cursor, edat, snd);
    edge_geom<<<EB, 256, 0, stream>>>(positions, W_rad, senders, receivers, perm,
                                      edat, snd);
    emb_kernel<<<HB, 256, 0, stream>>>(embed, species, h0);
    transpose_winv<<<32, 256, 0, stream>>>(W_inv1, W_inv2, WT1, WT2);

    // layer 1 (h gathered live from h0)
    mp_accum2<<<N_ATOMS, 64, 0, stream>>>(edat, snd, cursor, h0, Inv);
    mp_inv3<<<N_ATOMS / 16, 256, 0, stream>>>(Inv, WT1, h0, h1,
                                              w_out, comp_w, species, sids, accum, 0);
    // layer 2 (energy; h gathered live from h1)
    mp_accum2<<<N_ATOMS, 64, 0, stream>>>(edat, snd, cursor, h1, Inv);
    mp_inv3<<<N_ATOMS / 16, 256, 0, stream>>>(Inv, WT2, h0, h1,
                                              w_out, comp_w, species, sids, accum, 1);

    out_kernel<<<1, 64, 0, stream>>>(accum, out);
}

// Round 16
// 156.505 us; speedup vs baseline: 2.2214x; 1.0341x over previous
//
#include <hip/hip_runtime.h>

#define N_ATOMS 10000
#define N_EDGES 160000
#define N_STRUCT 8
#define D_PAD 48             // max slots per atom; P(Poisson(16) > 48) ~ 2e-7 overall
#define EDW 32               // floats per slot: [0..15]=sh, [16..31]=R (h gathered live)
#define N_SLOTS (N_ATOMS * D_PAD)
#define B4 4                 // slots per register batch
#define PI_F 3.14159265358979323846f
#define SROW 260             // padded LDS row stride (floats)

// ---------------- setup: cursor + accum + h0 + both W transposes (1 dispatch) ----------------

__global__ void setup_kernel(const float* __restrict__ embed, const int* __restrict__ species,
                             const float* __restrict__ Wi1, const float* __restrict__ Wi2,
                             float* __restrict__ h0, float* __restrict__ WT1,
                             float* __restrict__ WT2,
                             int* __restrict__ cursor, float* __restrict__ accum) {
    int i = blockIdx.x * blockDim.x + threadIdx.x;
    if (i < N_ATOMS) cursor[i] = i * D_PAD;
    if (i < N_STRUCT) accum[i] = 0.f;
    if (i < N_ATOMS * 16) {
        int a = i >> 4, c = i & 15;
        h0[i] = embed[species[a] * 16 + c];
    }
    if (i < 4096) {
        int k = i >> 4, c = i & 15;
        WT1[c * 256 + k] = Wi1[i];
        WT2[c * 256 + k] = Wi2[i];
    }
}

__global__ void scatter_kernel(const int* __restrict__ receivers, int* __restrict__ cursor,
                               int* __restrict__ perm) {
    int e = blockIdx.x * blockDim.x + threadIdx.x;
    if (e < N_EDGES) perm[e] = atomicAdd(&cursor[receivers[e]], 1);
}

// ---------------- edge geometry + pad-zero fused (post-scatter, disjoint writes) ----------
// Trig diet: the 8 Bessel sines are harmonics of one angle theta = pi*r/5 ->
// ONE __sincosf + Chebyshev recurrence (2 FMA per harmonic); fc's cosine is the
// same cos(theta) clamped. 9 transcendentals -> 1.

__global__ void geom_pad(const float* __restrict__ pos, const float* __restrict__ W_rad,
                         const int* __restrict__ senders, const int* __restrict__ receivers,
                         const int* __restrict__ perm, const int* __restrict__ cursor,
                         float* __restrict__ edat, int* __restrict__ snd) {
    int g = blockIdx.x * blockDim.x + threadIdx.x;

    // pad slots [cnt, ceil4(cnt)): zero sh+R and set a valid snd
    if (g < N_ATOMS * 3) {
        int a = g / 3, j = g % 3;
        int cnt = cursor[a] - a * D_PAD;
        if (cnt > D_PAD) cnt = D_PAD;
        int c4 = (cnt + B4 - 1) / B4 * B4;
        if (c4 > D_PAD) c4 = D_PAD;
        int slot = cnt + j;
        if (slot < c4) {
            float4 z = make_float4(0.f, 0.f, 0.f, 0.f);
            float4* p = (float4*)(edat + (size_t)(a * D_PAD + slot) * EDW);
            #pragma unroll
            for (int k = 0; k < 8; ++k) p[k] = z;
            snd[a * D_PAD + slot] = 0;
        }
    }

    if (g >= N_EDGES) return;
    const int e = g;
    int s = senders[e], rc = receivers[e];
    int p = perm[e];
    float dx = pos[rc * 3 + 0] - pos[s * 3 + 0];
    float dy = pos[rc * 3 + 1] - pos[s * 3 + 1];
    float dz = pos[rc * 3 + 2] - pos[s * 3 + 2];
    float r = sqrtf(dx * dx + dy * dy + dz * dz);
    float rr = fmaxf(r, 1e-6f);
    float inv = 1.0f / rr;
    float x = dx * inv, y = dy * inv, z = dz * inv;
    float x2 = x * x, y2 = y * y, z2 = z * z;
    float she[16];
    she[0]  = 0.28209479f;
    she[1]  = 0.48860251f * y;
    she[2]  = 0.48860251f * z;
    she[3]  = 0.48860251f * x;
    she[4]  = 1.09254843f * x * y;
    she[5]  = 1.09254843f * y * z;
    she[6]  = 0.31539157f * (3.0f * z2 - 1.0f);
    she[7]  = 1.09254843f * x * z;
    she[8]  = 0.54627422f * (x2 - y2);
    she[9]  = 0.59004359f * y * (3.0f * x2 - y2);
    she[10] = 2.89061144f * x * y * z;
    she[11] = 0.45704579f * y * (5.0f * z2 - 1.0f);
    she[12] = 0.37317633f * z * (5.0f * z2 - 3.0f);
    she[13] = 0.45704579f * x * (5.0f * z2 - 1.0f);
    she[14] = 1.44530572f * z * (x2 - y2);
    she[15] = 0.59004359f * x * (x2 - 3.0f * y2);
    float* ed = edat + (size_t)p * EDW;
    ((float4*)ed)[0] = make_float4(she[0], she[1], she[2], she[3]);
    ((float4*)ed)[1] = make_float4(she[4], she[5], she[6], she[7]);
    ((float4*)ed)[2] = make_float4(she[8], she[9], she[10], she[11]);
    ((float4*)ed)[3] = make_float4(she[12], she[13], she[14], she[15]);

    // one sincos; harmonics by Chebyshev; fc from the same cosine
    float theta = PI_F * rr * 0.2f;
    float s1, c1;
    __sincosf(theta, &s1, &c1);
    float fc = (r * 0.2f < 1.0f) ? 0.5f * (c1 + 1.0f) : 0.0f;
    const float kf = 0.6324555320336759f * inv * fc;   // sqrt(2/5)/r * fc
    float bfv[8];
    float sprev = 0.f, scur = s1;
    bfv[0] = kf * scur;
    const float twoc = 2.0f * c1;
    #pragma unroll
    for (int n = 1; n < 8; ++n) {
        float snext = fmaf(twoc, scur, -sprev);    // sin((n+1)t) = 2cos t sin(nt) - sin((n-1)t)
        sprev = scur; scur = snext;
        bfv[n] = kf * scur;
    }

    float Re[16];
    #pragma unroll
    for (int l = 0; l < 4; ++l) {
        #pragma unroll
        for (int n = 0; n < 4; ++n) {
            float acc = 0.0f;
            #pragma unroll
            for (int b = 0; b < 8; ++b) acc = fmaf(bfv[b], W_rad[l * 32 + b * 4 + n], acc);
            Re[l * 4 + n] = acc;
        }
    }
    ((float4*)ed)[4] = make_float4(Re[0], Re[1], Re[2], Re[3]);
    ((float4*)ed)[5] = make_float4(Re[4], Re[5], Re[6], Re[7]);
    ((float4*)ed)[6] = make_float4(Re[8], Re[9], Re[10], Re[11]);
    ((float4*)ed)[7] = make_float4(Re[12], Re[13], Re[14], Re[15]);
    snd[p] = s;
}

// ---------------- MP stage 1: accum + live h gather + inv (R15 passing, unchanged) ----------------

__global__ __launch_bounds__(64, 7) void mp_accum2(
    const float* __restrict__ edat, const int* __restrict__ snd,
    const int* __restrict__ cursor, const float* __restrict__ h_in,
    float* __restrict__ Inv)
{
    __shared__ __attribute__((aligned(16))) float wl[1024];   // squares [m*64 + k]
    const int lane = threadIdx.x;                  // block = 1 wave = 1 atom
    const int atom = blockIdx.x;                   // 10000 blocks
    const int m = lane >> 2, cg = lane & 3;
    const int l = (m >= 9) ? 3 : (m >= 4) ? 2 : (m >= 1) ? 1 : 0;
    const int l4 = l * 4, cg4 = cg * 4;

    int cnt = cursor[atom] - atom * D_PAD;
    if (cnt > D_PAD) cnt = D_PAD;
    const int nb = (cnt + B4 - 1) / B4;            // real 4-slot batches (pads zeroed)

    int sv = 0;
    if (lane < D_PAD) sv = snd[atom * D_PAD + lane];

    const float* strip = edat + (size_t)atom * (D_PAD * EDW);

    float acc[4][4];  // [n][j] ; A[m][n*16 + cg*4+j]
    #pragma unroll
    for (int n = 0; n < 4; ++n)
        #pragma unroll
        for (int j = 0; j < 4; ++j) acc[n][j] = 0.f;

    for (int b = 0; b < nb; ++b) {
        const int s0 = b * B4;
        const float* bp = strip + s0 * EDW;
        float  shv[B4];
        float4 rv[B4];
        float4 hv[B4];
        #pragma unroll
        for (int q = 0; q < B4; ++q) {
            const float* eq = bp + q * EDW;
            shv[q] = eq[m];
            rv[q]  = *(const float4*)(eq + 16 + l4);
            hv[q]  = *(const float4*)(h_in + (size_t)__shfl(sv, s0 + q) * 16 + cg4);
        }
        #pragma unroll
        for (int q = 0; q < B4; ++q) {
            float hvj[4] = {hv[q].x, hv[q].y, hv[q].z, hv[q].w};
            float rvn[4] = {rv[q].x, rv[q].y, rv[q].z, rv[q].w};
            #pragma unroll
            for (int j = 0; j < 4; ++j) {
                float ww = shv[q] * hvj[j];
                #pragma unroll
                for (int n = 0; n < 4; ++n)
                    acc[n][j] = fmaf(ww, rvn[n], acc[n][j]);
            }
        }
    }

    // squares -> LDS (same-wave DS is in-order; k = n*16+c in [0,64))
    #pragma unroll
    for (int n = 0; n < 4; ++n)
        *(float4*)&wl[m * 64 + n * 16 + cg4] =
            make_float4(acc[n][0] * acc[n][0], acc[n][1] * acc[n][1],
                        acc[n][2] * acc[n][2], acc[n][3] * acc[n][3]);

    // STATIC column sums (proven idiom): lane = k
    const float* T = wl;
    const int k = lane;
    float s0v = T[k];
    float s1v = T[64 + k] + T[128 + k] + T[192 + k];
    float s2v = T[256 + k] + T[320 + k] + T[384 + k] + T[448 + k] + T[512 + k];
    float s3v = T[576 + k] + T[640 + k] + T[704 + k] + T[768 + k]
              + T[832 + k] + T[896 + k] + T[960 + k];
    float* ip = Inv + (size_t)atom * 256;
    ip[k]       = s0v;
    ip[64 + k]  = s1v * 0.57735026918962576f;
    ip[128 + k] = s2v * 0.44721359549995794f;
    ip[192 + k] = s3v * 0.37796447300922720f;
}

// ---------------- MP stage 2: h / energy from inv (R15 passing, unchanged) ----------------

__global__ __launch_bounds__(256, 2) void mp_inv3(
    const float* __restrict__ Inv,
    const float* __restrict__ W_invT,
    const float* __restrict__ cemb, float* __restrict__ h_out,
    const float* __restrict__ w_out, const float* __restrict__ comp_w,
    const int* __restrict__ species, const int* __restrict__ sids,
    float* __restrict__ accum, int do_energy)
{
    __shared__ __attribute__((aligned(16))) float sWT[16 * SROW];
    __shared__ __attribute__((aligned(16))) float sInv[16 * SROW];
    __shared__ float sE[16];
    const int t = threadIdx.x;
    const int w = t >> 6, lane = t & 63;
    const int blk = blockIdx.x;                    // 625 blocks x 16 atoms

    if (do_energy) {
        #pragma unroll
        for (int g = 0; g < 4; ++g) {
            const int atomL = g * 4 + w;
            const size_t base = (size_t)(blk * 16 + atomL) * 256;
            float i0 = Inv[base + lane];
            float i1 = Inv[base + 64 + lane];
            float i2 = Inv[base + 128 + lane];
            float i3 = Inv[base + 192 + lane];
            float pe = i0 * w_out[lane] + i1 * w_out[64 + lane]
                     + i2 * w_out[128 + lane] + i3 * w_out[192 + lane];
            #pragma unroll
            for (int off = 32; off > 0; off >>= 1) pe += __shfl_down(pe, off);
            if (lane == 0) sE[atomL] = pe;
        }
        __syncthreads();
        if (t == 0) {                              // run-compressed atomics (sids sorted)
            const int base = blk * 16;
            int cursid = sids[base];
            float run = 0.f;
            for (int a = 0; a < 16; ++a) {
                int sid = sids[base + a];
                float e = sE[a] + comp_w[species[base + a]];
                if (sid != cursid) { atomicAdd(&accum[cursid], run); run = 0.f; cursid = sid; }
                run += e;
            }
            atomicAdd(&accum[cursid], run);
        }
    } else {
        #pragma unroll
        for (int i = 0; i < 16; ++i) {             // coalesced loads -> LDS
            int idx = i * 256 + t;
            int row = idx >> 8, col = idx & 255;
            sWT[row * SROW + col]  = W_invT[idx];
            sInv[row * SROW + col] = Inv[(size_t)blk * 4096 + idx];
        }
        __syncthreads();
        // h[a][c] = (sum_k inv[a][k] * W[k][c]) * cemb : LDS-broadcast GEMM
        const int aL = t >> 4, c = t & 15;
        const float* ivp = &sInv[aL * SROW];
        const float* wvp = &sWT[c * SROW];
        float p = 0.f;
        #pragma unroll
        for (int kk = 0; kk < 64; ++kk) {
            float4 iv = *(const float4*)&ivp[kk * 4];
            float4 wv = *(const float4*)&wvp[kk * 4];
            p = fmaf(iv.x, wv.x, p);
            p = fmaf(iv.y, wv.y, p);
            p = fmaf(iv.z, wv.z, p);
            p = fmaf(iv.w, wv.w, p);
        }
        const int gi = blk * 256 + t;              // = atom*16 + c : full-line store
        h_out[gi] = p * cemb[gi];
    }
}

__global__ void out_kernel(const float* __restrict__ accum, float* __restrict__ out) {
    int t = threadIdx.x;
    if (t < N_STRUCT) out[t] = accum[t];
}

// ---------------- launch (8 dispatches) ----------------

extern "C" void kernel_launch(void* const* d_in, const int* in_sizes, int n_in,
                              void* d_out, int out_size, void* d_ws, size_t ws_size,
                              hipStream_t stream) {
    const float* positions = (const float*)d_in[0];
    const float* embed     = (const float*)d_in[1];
    const float* W_rad     = (const float*)d_in[2];
    const float* W_inv1    = (const float*)d_in[3];
    const float* W_inv2    = (const float*)d_in[4];
    const float* w_out     = (const float*)d_in[5];
    const float* comp_w    = (const float*)d_in[6];
    const int* senders    = (const int*)d_in[7];
    const int* receivers  = (const int*)d_in[8];
    const int* species    = (const int*)d_in[9];
    const int* sids       = (const int*)d_in[10];
    float* out = (float*)d_out;

    char* ws = (char*)d_ws;
    size_t off = 0;
    auto alloc = [&](size_t bytes) -> void* {
        void* p = ws + off;
        off = (off + bytes + 255) & ~(size_t)255;
        return p;
    };
    float* edat     = (float*)alloc((size_t)N_SLOTS * EDW * 4);     // 61.4 MB
    float* Inv      = (float*)alloc((size_t)N_ATOMS * 256 * 4);     // 10.24 MB
    float* h0       = (float*)alloc((size_t)N_ATOMS * 16 * 4);
    float* h1       = (float*)alloc((size_t)N_ATOMS * 16 * 4);
    int*   cursor   = (int*)alloc((size_t)N_ATOMS * 4);
    int*   perm     = (int*)alloc((size_t)N_EDGES * 4);
    int*   snd      = (int*)alloc((size_t)N_SLOTS * 4);
    float* accum    = (float*)alloc(8 * 4);
    float* WT1      = (float*)alloc(4096 * 4);
    float* WT2      = (float*)alloc(4096 * 4);

    const int EB = (N_EDGES + 255) / 256;            // 625

    setup_kernel<<<EB, 256, 0, stream>>>(embed, species, W_inv1, W_inv2,
                                         h0, WT1, WT2, cursor, accum);
    scatter_kernel<<<EB, 256, 0, stream>>>(receivers, cursor, perm);
    geom_pad<<<EB, 256, 0, stream>>>(positions, W_rad, senders, receivers,
                                     perm, cursor, edat, snd);

    // layer 1 (h gathered live from h0)
    mp_accum2<<<N_ATOMS, 64, 0, stream>>>(edat, snd, cursor, h0, Inv);
    mp_inv3<<<N_ATOMS / 16, 256, 0, stream>>>(Inv, WT1, h0, h1,
                                              w_out, comp_w, species, sids, accum, 0);
    // layer 2 (energy; h gathered live from h1)
    mp_accum2<<<N_ATOMS, 64, 0, stream>>>(edat, snd, cursor, h1, Inv);
    mp_inv3<<<N_ATOMS / 16, 256, 0, stream>>>(Inv, WT2, h0, h1,
                                              w_out, comp_w, species, sids, accum, 1);

    out_kernel<<<1, 64, 0, stream>>>(accum, out);
}